// Round 12
// baseline (332.981 us; speedup 1.0000x reference)
//
#include <hip/hip_runtime.h>
#include <math.h>

static constexpr int B  = 16384;
static constexpr int F  = 256;
static constexpr int NQ = 2048;
static constexpr int TS = 16;
static constexpr int KTOP = 8;
static constexpr int SPD = 272;   // 256 + 16
static constexpr int SPH = 68;
static constexpr int CD  = 278;   // 256+1+3+16+2
static constexpr int CH  = 69;

typedef __attribute__((ext_vector_type(8))) short bf16x8;
typedef __attribute__((ext_vector_type(4))) float f32x4;

__device__ inline short f2bf(float f) {
    unsigned u = __builtin_bit_cast(unsigned, f);
    unsigned r = (u + 0x7FFF + ((u >> 16) & 1)) >> 16;   // RNE
    return (short)r;
}
__device__ inline float bf2f(short s) {
    return __builtin_bit_cast(float, ((unsigned)(unsigned short)s) << 16);
}

__device__ inline float fast_tanh(float o) {
    o = fminf(fmaxf(o, -15.0f), 15.0f);
    float e = __expf(2.0f * o);
    return (e - 1.0f) / (e + 1.0f);
}

// ---------------------------------------------------------------------------
// k_prepall: bf16 W^T buffers (padded) + qs transpose (unchanged)
// ---------------------------------------------------------------------------
__device__ inline void prep_one(const float* W, short* T, int local,
                                int K, int N, int KP) {
    const int n = local / KP, k = local - n * KP;
    T[local] = (k < K && n < N) ? f2bf(W[k * N + n]) : (short)0;
}

__global__ __launch_bounds__(256) void k_prepall(
    const float* __restrict__ gate_w1, const float* __restrict__ gate_w2,
    const float* __restrict__ bb_w,    const float* __restrict__ safe_w1,
    const float* __restrict__ spec_w1, const float* __restrict__ conf_w1,
    const float* __restrict__ qs,
    short* __restrict__ w1t, short* __restrict__ w2t, short* __restrict__ bbt,
    short* __restrict__ sw1t, short* __restrict__ spw1t, short* __restrict__ cfw1t,
    float* __restrict__ qs_t)
{
    const int idx = blockIdx.x * 256 + threadIdx.x;
    if (idx < 32768)       prep_one(gate_w1, w1t,  idx,           256, 128, 256);
    else if (idx < 65536)  prep_one(gate_w2, w2t,  idx - 32768,   128, 256, 128);
    else if (idx < 131072) prep_one(bb_w,    bbt,  idx - 65536,   256, 256, 256);
    else if (idx < 163840) prep_one(safe_w1, sw1t, idx - 131072,  256, 128, 256);
    else if (idx < 200704) prep_one(spec_w1, spw1t, idx - 163840, 272, 68, 288);
    else if (idx < 237568) prep_one(conf_w1, cfw1t, idx - 200704, 278, 69, 288);
    else if (idx < 761856) {
        const int local = idx - 237568;
        const int f = local >> 11, q = local & 2047;
        qs_t[local] = qs[q * 256 + f];
    }
}

// ---------------------------------------------------------------------------
// k_calib9 (unchanged from R11 — 84us, near structural floor)
// ---------------------------------------------------------------------------
__global__ __launch_bounds__(256) void k_calib9(
    const float* __restrict__ x_num, const float* __restrict__ center,
    const float* __restrict__ scale, const float* __restrict__ qs,
    const float* __restrict__ qs_t,
    const float* __restrict__ sw1, const float* __restrict__ sb1,
    const float* __restrict__ sw2, const float* __restrict__ sb2,
    const float* __restrict__ sw3, const float* __restrict__ sb3,
    short* __restrict__ x_bf)
{
    __shared__ float cq[63 * 128];          // 31.5 KB coarse boundaries
    const int tid = threadIdx.x;
    const int fl = tid & 127;
    const int half = tid >> 7;
    const int fg = blockIdx.y;
    const int f = fg * 128 + fl;

    for (int idx = tid; idx < 63 * 128; idx += 256) {
        const int j = idx >> 7, f2 = idx & 127;
        cq[idx] = qs[(32 * (j + 1)) * 256 + fg * 128 + f2];
    }
    __syncthreads();

    const float c = center[f];
    const float inv_sc = 1.0f / scale[f];
    const float* colp = qs_t + (long)f * NQ;
    const long row_base = (long)blockIdx.x * 32 + half * 16;

#pragma unroll 1
    for (int grp = 0; grp < 2; ++grp) {
        const long r0 = row_base + grp * 8;
        float x[8], xr[8];
#pragma unroll
        for (int i = 0; i < 8; ++i) {
            x[i] = x_num[(r0 + i) * F + f];
            xr[i] = (x[i] - c) * inv_sc;
        }
        int lo[8], hi[8];
#pragma unroll
        for (int i = 0; i < 8; ++i) { lo[i] = 0; hi[i] = 63; }
#pragma unroll
        for (int it = 0; it < 6; ++it) {
            float qv[8]; int mid[8];
#pragma unroll
            for (int i = 0; i < 8; ++i) {
                mid[i] = (lo[i] + hi[i]) >> 1;
                qv[i] = cq[mid[i] * 128 + fl];
            }
#pragma unroll
            for (int i = 0; i < 8; ++i) {
                if (qv[i] < x[i]) lo[i] = mid[i] + 1; else hi[i] = mid[i];
            }
        }
        int base[8];
        {
            float pm[8];
#pragma unroll
            for (int i = 0; i < 8; ++i) pm[i] = colp[lo[i] * 32 + 16];
#pragma unroll
            for (int i = 0; i < 8; ++i)
                base[i] = lo[i] * 32 + ((pm[i] < x[i]) ? 16 : 0);
        }
        float xq[8];
#pragma unroll
        for (int i = 0; i < 8; ++i) {
            const float4* wp = reinterpret_cast<const float4*>(&colp[base[i]]);
            const float4 a = wp[0], b = wp[1], d = wp[2], e = wp[3];
            int cN = 0;
            cN += (a.x < x[i]); cN += (a.y < x[i]); cN += (a.z < x[i]); cN += (a.w < x[i]);
            cN += (b.x < x[i]); cN += (b.y < x[i]); cN += (b.z < x[i]); cN += (b.w < x[i]);
            cN += (d.x < x[i]); cN += (d.y < x[i]); cN += (d.z < x[i]); cN += (d.w < x[i]);
            cN += (e.x < x[i]); cN += (e.y < x[i]); cN += (e.z < x[i]); cN += (e.w < x[i]);
            const int rank = base[i] + cN;
            xq[i] = fminf((float)rank * (1.0f / (float)(NQ - 1)), 1.0f);
        }
#pragma unroll
        for (int hgrp = 0; hgrp < 2; ++hgrp) {
            const int o4 = hgrp * 4;
            float h2[4][16];
#pragma unroll
            for (int j = 0; j < 16; ++j) {
                const float bb = sb2[j];
#pragma unroll
                for (int i = 0; i < 4; ++i) h2[i][j] = bb;
            }
#pragma unroll 4
            for (int i16 = 0; i16 < 16; ++i16) {
                const float w0 = sw1[i16], w1v = sw1[16 + i16], w2v = sw1[32 + i16];
                const float bb = sb1[i16];
                float h1v[4];
#pragma unroll
                for (int i = 0; i < 4; ++i)
                    h1v[i] = fmaxf(bb + x[o4 + i] * w0 + xr[o4 + i] * w1v + xq[o4 + i] * w2v, 0.0f);
                float wv[16];
                const float4* wr = reinterpret_cast<const float4*>(&sw2[i16 * 16]);
                *reinterpret_cast<float4*>(&wv[0])  = wr[0];
                *reinterpret_cast<float4*>(&wv[4])  = wr[1];
                *reinterpret_cast<float4*>(&wv[8])  = wr[2];
                *reinterpret_cast<float4*>(&wv[12]) = wr[3];
#pragma unroll
                for (int j = 0; j < 16; ++j) {
#pragma unroll
                    for (int i = 0; i < 4; ++i) h2[i][j] += h1v[i] * wv[j];
                }
            }
            const float b3 = sb3[0];
            float o[4] = {b3, b3, b3, b3};
#pragma unroll
            for (int j = 0; j < 16; ++j) {
                const float w3v = sw3[j];
#pragma unroll
                for (int i = 0; i < 4; ++i) o[i] += fmaxf(h2[i][j], 0.0f) * w3v;
            }
#pragma unroll
            for (int i = 0; i < 4; ++i) {
                const float xc = x[o4 + i] + 0.1f * fast_tanh(o[i]);
                x_bf[(r0 + o4 + i) * F + f] = f2bf(xc);
            }
        }
    }
}

// ---------------------------------------------------------------------------
// k_mega: one kernel for gate1 -> gate2 -> topk/stats/z -> backbone -> heads.
// 16 rows/block, 256 threads (4 waves), grid B/16 = 1024.  LDS ~41 KB.
// ---------------------------------------------------------------------------
static constexpr int MR   = 16;
static constexpr int GST  = 260;  // s_g fp32 stride (words)
static constexpr int AST  = 312;  // s_u1 bf16 stride (xg + head-A share)
static constexpr int HBST = 264;  // s_hbb bf16 stride
static constexpr int C1ST = 136;  // s_c1 bf16 stride

template<int KP>
__device__ __forceinline__ void head_mfma16(
    const short* sa, const short* __restrict__ Wt,
    const float* __restrict__ b1v, const float* __restrict__ w2v, int Nreal,
    float (*s_red)[16], int wave, int sub, int quad)
{
    f32x4 acc[2];
#pragma unroll
    for (int t = 0; t < 2; ++t) acc[t] = (f32x4){0, 0, 0, 0};
#pragma unroll
    for (int k0 = 0; k0 < KP; k0 += 32) {
        const bf16x8 af = *reinterpret_cast<const bf16x8*>(
            &sa[sub * AST + k0 + quad * 8]);
#pragma unroll
        for (int t = 0; t < 2; ++t) {
            const int col = wave * 32 + t * 16 + sub;
            const bf16x8 bf = *reinterpret_cast<const bf16x8*>(
                &Wt[(long)col * KP + k0 + quad * 8]);
            acc[t] = __builtin_amdgcn_mfma_f32_16x16x32_bf16(af, bf, acc[t], 0, 0, 0);
        }
    }
    float rsum[4] = {0, 0, 0, 0};
#pragma unroll
    for (int t = 0; t < 2; ++t) {
        const int col = wave * 32 + t * 16 + sub;
        const float bb = (col < Nreal) ? b1v[col] : 0.0f;
        const float ww = (col < Nreal) ? w2v[col] : 0.0f;
#pragma unroll
        for (int rr = 0; rr < 4; ++rr)
            rsum[rr] += fmaxf(acc[t][rr] + bb, 0.0f) * ww;
    }
#pragma unroll
    for (int rr = 0; rr < 4; ++rr)
        for (int m = 1; m < 16; m <<= 1) rsum[rr] += __shfl_xor(rsum[rr], m);
    if (sub == 0) {
#pragma unroll
        for (int rr = 0; rr < 4; ++rr)
            s_red[wave][quad * 4 + rr] = rsum[rr];
    }
}

__global__ __launch_bounds__(256) void k_mega(
    const short* __restrict__ x_bf,
    const short* __restrict__ w1t, const float* __restrict__ gate_b1,
    const short* __restrict__ w2t, const float* __restrict__ gate_b2,
    const short* __restrict__ bbt, const float* __restrict__ bb_b,
    const float* __restrict__ base_w, const float* __restrict__ base_b,
    const float* __restrict__ tw1, const float* __restrict__ tb1,
    const float* __restrict__ tw2, const float* __restrict__ tb2,
    const float* __restrict__ safe_lg, const float* __restrict__ safe_lb,
    const short* __restrict__ sw1t, const float* __restrict__ safe_b1,
    const float* __restrict__ safe_w2, const float* __restrict__ safe_b2,
    const float* __restrict__ spec_lg, const float* __restrict__ spec_lb,
    const short* __restrict__ spw1t, const float* __restrict__ spec_b1,
    const float* __restrict__ spec_w2, const float* __restrict__ spec_b2,
    const float* __restrict__ conf_lg, const float* __restrict__ conf_lb,
    const short* __restrict__ cfw1t, const float* __restrict__ conf_b1,
    const float* __restrict__ conf_w2, const float* __restrict__ conf_b2,
    float* __restrict__ out)
{
    __shared__ float s_g[MR * GST];       // 16.6 KB  gate fp32 (exact topk)
    __shared__ short s_u1[MR * AST];      // 10.0 KB  x_gated, later head-A
    __shared__ short s_c1[MR * C1ST];     // 4.25 KB  h1 bf16
    __shared__ short s_hbb[MR * HBST];    // 8.25 KB  h_base bf16
    __shared__ float s_z[MR * 16];        // 1 KB
    __shared__ float s_sc[MR * 16];       // 1 KB  per-row scalars
    __shared__ float s_redS[4][16], s_redSS[4][16], s_redY[4][16];

    const int tid = threadIdx.x;
    const int wave = tid >> 6, lane = tid & 63;
    const int sub = lane & 15, quad = lane >> 4;
    const long row0 = (long)blockIdx.x * MR;

    // ---- P0: gate1 = relu(x @ W1 + b1), 16x128; wave owns 32 cols ----
    {
        f32x4 acc[2];
#pragma unroll
        for (int t = 0; t < 2; ++t) acc[t] = (f32x4){0, 0, 0, 0};
#pragma unroll
        for (int k0 = 0; k0 < 256; k0 += 32) {
            const bf16x8 af = *reinterpret_cast<const bf16x8*>(
                &x_bf[(row0 + sub) * 256 + k0 + quad * 8]);
#pragma unroll
            for (int t = 0; t < 2; ++t) {
                const int col = wave * 32 + t * 16 + sub;
                const bf16x8 bf = *reinterpret_cast<const bf16x8*>(
                    &w1t[(long)col * 256 + k0 + quad * 8]);
                acc[t] = __builtin_amdgcn_mfma_f32_16x16x32_bf16(af, bf, acc[t], 0, 0, 0);
            }
        }
#pragma unroll
        for (int t = 0; t < 2; ++t) {
            const int col = wave * 32 + t * 16 + sub;
            const float bb = gate_b1[col];
#pragma unroll
            for (int r = 0; r < 4; ++r)
                s_c1[(quad * 4 + r) * C1ST + col] = f2bf(fmaxf(acc[t][r] + bb, 0.0f));
        }
    }
    __syncthreads();

    // ---- P1: gate2 = sigmoid(h1 @ W2 + b2), 16x256; wave owns 64 cols ----
    {
        f32x4 acc[4];
#pragma unroll
        for (int t = 0; t < 4; ++t) acc[t] = (f32x4){0, 0, 0, 0};
#pragma unroll
        for (int k0 = 0; k0 < 128; k0 += 32) {
            const bf16x8 af = *reinterpret_cast<const bf16x8*>(
                &s_c1[sub * C1ST + k0 + quad * 8]);
#pragma unroll
            for (int t = 0; t < 4; ++t) {
                const int col = wave * 64 + t * 16 + sub;
                const bf16x8 bf = *reinterpret_cast<const bf16x8*>(
                    &w2t[(long)col * 128 + k0 + quad * 8]);
                acc[t] = __builtin_amdgcn_mfma_f32_16x16x32_bf16(af, bf, acc[t], 0, 0, 0);
            }
        }
#pragma unroll
        for (int t = 0; t < 4; ++t) {
            const int col = wave * 64 + t * 16 + sub;
            const float bb = gate_b2[col];
#pragma unroll
            for (int r = 0; r < 4; ++r)
                s_g[(quad * 4 + r) * GST + col] =
                    1.0f / (1.0f + __expf(-(acc[t][r] + bb)));
        }
    }
    __syncthreads();

    // ---- P2: per-wave topk/stats/z for rows wave*4 .. wave*4+3 ----
#pragma unroll 1
    for (int rr = 0; rr < 4; ++rr) {
        const int row = wave * 4 + rr;
        float gv[4];
#pragma unroll
        for (int i = 0; i < 4; ++i) gv[i] = s_g[row * GST + lane + 64 * i];

        float s = gv[0] + gv[1] + gv[2] + gv[3];
        float mx = fmaxf(fmaxf(gv[0], gv[1]), fmaxf(gv[2], gv[3]));
        for (int m = 32; m; m >>= 1) {
            s  += __shfl_xor(s, m);
            mx  = fmaxf(mx, __shfl_xor(mx, m));
        }
        const float mean = s * (1.0f / 256.0f);
        float vs = 0.0f;
#pragma unroll
        for (int i = 0; i < 4; ++i) { float d = gv[i] - mean; vs += d * d; }
        for (int m = 32; m; m >>= 1) vs += __shfl_xor(vs, m);
        const float stdv = sqrtf(vs * (1.0f / 256.0f));

        float cur[4]; int curi[4];
#pragma unroll
        for (int i = 0; i < 4; ++i) { cur[i] = gv[i]; curi[i] = lane + 64 * i; }
        float tv[KTOP]; int ti[KTOP]; float vsum = 0.0f;
        for (int r = 0; r < KTOP; ++r) {
            float bv = cur[0]; int bi = curi[0];
#pragma unroll
            for (int i = 1; i < 4; ++i)
                if (cur[i] > bv || (cur[i] == bv && curi[i] < bi)) { bv = cur[i]; bi = curi[i]; }
            for (int m = 32; m; m >>= 1) {
                float ov = __shfl_xor(bv, m);
                int   oi = __shfl_xor(bi, m);
                if (ov > bv || (ov == bv && oi < bi)) { bv = ov; bi = oi; }
            }
            tv[r] = bv; ti[r] = bi; vsum += bv;
#pragma unroll
            for (int i = 0; i < 4; ++i) if (curi[i] == bi) cur[i] = -INFINITY;
        }
        const float denom = 1.0f / (vsum + 1e-6f);

        float hm = 0.0f;
        if (lane < 16) {
            for (int k = 0; k < KTOP; ++k) {
                const float xk = bf2f(x_bf[(row0 + row) * 256 + ti[k]]);
                const float xw = xk * (tv[k] * denom);
                hm += fmaxf(xw * tw1[lane] + tb1[lane], 0.0f);
            }
            hm *= (1.0f / (float)KTOP);
        }
        float z = (lane < 16) ? tb2[lane] : 0.0f;
#pragma unroll
        for (int j = 0; j < 16; ++j) {
            const float hj = __shfl(hm, j);
            if (lane < 16) z += hj * tw2[j * 16 + lane];
        }
        if (lane < 16) s_z[row * 16 + lane] = z;
        float zz = (lane < 16) ? z : 0.0f;
        float zz2 = zz * zz;
#pragma unroll
        for (int m = 1; m < 16; m <<= 1) {
            zz += __shfl_xor(zz, m); zz2 += __shfl_xor(zz2, m);
        }
        if (lane == 0) {
            float* sc = &s_sc[row * 16];
            sc[2] = zz; sc[3] = zz2;
            sc[13] = mean; sc[14] = mx; sc[15] = stdv;
        }
    }
    __syncthreads();

    // ---- P3: build x_gated bf16 into s_u1 ----
    for (int idx = tid; idx < MR * 128; idx += 256) {
        const int r = idx >> 7, k = (idx & 127) * 2;
        const unsigned xp = *reinterpret_cast<const unsigned*>(
            &x_bf[(row0 + r) * 256 + k]);
        const float x0 = bf2f((short)(xp & 0xFFFF));
        const float x1 = bf2f((short)(xp >> 16));
        const float v0 = x0 * s_g[r * GST + k];
        const float v1 = x1 * s_g[r * GST + k + 1];
        const unsigned pk = (unsigned)(unsigned short)f2bf(v0) |
                            ((unsigned)(unsigned short)f2bf(v1) << 16);
        *reinterpret_cast<unsigned*>(&s_u1[r * AST + k]) = pk;
    }
    __syncthreads();

    // ---- P4: backbone = relu(xg @ BB + b), 16x256; wave owns 64 cols ----
    {
        f32x4 acc[4];
#pragma unroll
        for (int t = 0; t < 4; ++t) acc[t] = (f32x4){0, 0, 0, 0};
#pragma unroll
        for (int k0 = 0; k0 < 256; k0 += 32) {
            const bf16x8 af = *reinterpret_cast<const bf16x8*>(
                &s_u1[sub * AST + k0 + quad * 8]);
#pragma unroll
            for (int t = 0; t < 4; ++t) {
                const int col = wave * 64 + t * 16 + sub;
                const bf16x8 bf = *reinterpret_cast<const bf16x8*>(
                    &bbt[(long)col * 256 + k0 + quad * 8]);
                acc[t] = __builtin_amdgcn_mfma_f32_16x16x32_bf16(af, bf, acc[t], 0, 0, 0);
            }
        }
        float Sp[4] = {0,0,0,0}, SSp[4] = {0,0,0,0}, Yp[4] = {0,0,0,0};
#pragma unroll
        for (int t = 0; t < 4; ++t) {
            const int col = wave * 64 + t * 16 + sub;
            const float bb = bb_b[col];
            const float bw = base_w[col];
#pragma unroll
            for (int r = 0; r < 4; ++r) {
                const float h = fmaxf(acc[t][r] + bb, 0.0f);
                s_hbb[(quad * 4 + r) * HBST + col] = f2bf(h);
                Sp[r] += h; SSp[r] += h * h; Yp[r] += h * bw;
            }
        }
#pragma unroll
        for (int r = 0; r < 4; ++r) {
#pragma unroll
            for (int m = 1; m < 16; m <<= 1) {
                Sp[r] += __shfl_xor(Sp[r], m);
                SSp[r] += __shfl_xor(SSp[r], m);
                Yp[r] += __shfl_xor(Yp[r], m);
            }
        }
        if (sub == 0) {
#pragma unroll
            for (int r = 0; r < 4; ++r) {
                s_redS[wave][quad * 4 + r] = Sp[r];
                s_redSS[wave][quad * 4 + r] = SSp[r];
                s_redY[wave][quad * 4 + r] = Yp[r];
            }
        }
    }
    __syncthreads();

    // ---- P5: per-row scalars ----
    if (tid < MR) {
        float S = 0, SS = 0, Y = 0;
#pragma unroll
        for (int w = 0; w < 4; ++w) {
            S += s_redS[w][tid]; SS += s_redSS[w][tid]; Y += s_redY[w][tid];
        }
        float* sc = &s_sc[tid * 16];
        sc[0] = S; sc[1] = SS;
        sc[4] = Y + base_b[0];
        const float mu = S * (1.0f / 256.0f);
        sc[5] = mu;
        sc[6] = rsqrtf(SS * (1.0f / 256.0f) - mu * mu + 1e-5f);
        const float musp = (S + sc[2]) * (1.0f / (float)SPD);
        sc[7] = musp;
        sc[8] = rsqrtf((SS + sc[3]) * (1.0f / (float)SPD) - musp * musp + 1e-5f);
    }
    __syncthreads();

    // ---- P6: safe head ----
    for (int idx = tid; idx < MR * 128; idx += 256) {
        const int r = idx >> 7, k = (idx & 127) * 2;
        const float mu = s_sc[r * 16 + 5], rs = s_sc[r * 16 + 6];
        const float h0 = bf2f(s_hbb[r * HBST + k]);
        const float h1 = bf2f(s_hbb[r * HBST + k + 1]);
        const float v0 = (h0 - mu) * rs * safe_lg[k] + safe_lb[k];
        const float v1 = (h1 - mu) * rs * safe_lg[k + 1] + safe_lb[k + 1];
        const unsigned pk = (unsigned)(unsigned short)f2bf(v0) |
                            ((unsigned)(unsigned short)f2bf(v1) << 16);
        *reinterpret_cast<unsigned*>(&s_u1[r * AST + k]) = pk;
    }
    __syncthreads();
    head_mfma16<256>(s_u1, sw1t, safe_b1, safe_w2, 128, s_redS, wave, sub, quad);
    __syncthreads();

    // ---- P7: dsafe + spec A-build ----
    if (tid < MR)
        s_sc[tid * 16 + 9] = s_redS[0][tid] + s_redS[1][tid] + s_redS[2][tid] +
                             s_redS[3][tid] + safe_b2[0];
    for (int idx = tid; idx < MR * 144; idx += 256) {
        const int r = idx / 144, k = (idx - r * 144) * 2;
        const float mu = s_sc[r * 16 + 7], rs = s_sc[r * 16 + 8];
        float vv[2];
#pragma unroll
        for (int h = 0; h < 2; ++h) {
            const int kk = k + h;
            float raw = (kk < 256) ? bf2f(s_hbb[r * HBST + kk])
                       : (kk < SPD) ? s_z[r * 16 + kk - 256] : 0.0f;
            vv[h] = (kk < SPD) ? (raw - mu) * rs * spec_lg[kk] + spec_lb[kk] : 0.0f;
        }
        const unsigned pk = (unsigned)(unsigned short)f2bf(vv[0]) |
                            ((unsigned)(unsigned short)f2bf(vv[1]) << 16);
        *reinterpret_cast<unsigned*>(&s_u1[r * AST + k]) = pk;
    }
    __syncthreads();
    head_mfma16<288>(s_u1, spw1t, spec_b1, spec_w2, SPH, s_redS, wave, sub, quad);
    __syncthreads();

    // ---- P8: dspec + conf stats ----
    if (tid < MR) {
        float* sc = &s_sc[tid * 16];
        const float dsp = s_redS[0][tid] + s_redS[1][tid] + s_redS[2][tid] +
                          s_redS[3][tid] + spec_b2[0];
        sc[10] = dsp;
        const float yb = sc[4];
        const float gm = sc[13], gx = sc[14], gs = sc[15];
        const float ads = fabsf(sc[9]), adp = fabsf(dsp);
        const float es = yb + gm + gx + gs + ads + adp;
        const float eq = yb * yb + gm * gm + gx * gx + gs * gs + ads * ads + adp * adp;
        const float muc = (sc[0] + sc[2] + es) * (1.0f / (float)CD);
        sc[11] = muc;
        sc[12] = rsqrtf((sc[1] + sc[3] + eq) * (1.0f / (float)CD) - muc * muc + 1e-5f);
    }
    __syncthreads();

    // ---- P9: conf head ----
    for (int idx = tid; idx < MR * 144; idx += 256) {
        const int r = idx / 144, k = (idx - r * 144) * 2;
        const float mu = s_sc[r * 16 + 11], rs = s_sc[r * 16 + 12];
        float vv[2];
#pragma unroll
        for (int h = 0; h < 2; ++h) {
            const int kk = k + h;
            float raw;
            if (kk < 256)       raw = bf2f(s_hbb[r * HBST + kk]);
            else if (kk == 256) raw = s_sc[r * 16 + 4];
            else if (kk == 257) raw = s_sc[r * 16 + 13];
            else if (kk == 258) raw = s_sc[r * 16 + 14];
            else if (kk == 259) raw = s_sc[r * 16 + 15];
            else if (kk < 276)  raw = s_z[r * 16 + kk - 260];
            else if (kk == 276) raw = fabsf(s_sc[r * 16 + 9]);
            else if (kk == 277) raw = fabsf(s_sc[r * 16 + 10]);
            else                raw = 0.0f;
            vv[h] = (kk < CD) ? (raw - mu) * rs * conf_lg[kk] + conf_lb[kk] : 0.0f;
        }
        const unsigned pk = (unsigned)(unsigned short)f2bf(vv[0]) |
                            ((unsigned)(unsigned short)f2bf(vv[1]) << 16);
        *reinterpret_cast<unsigned*>(&s_u1[r * AST + k]) = pk;
    }
    __syncthreads();
    head_mfma16<288>(s_u1, cfw1t, conf_b1, conf_w2, CH, s_redS, wave, sub, quad);
    __syncthreads();

    // ---- P10: output ----
    if (tid < MR) {
        const float* sc = &s_sc[tid * 16];
        const float gamma = 1.0f / (1.0f + __expf(
            -(s_redS[0][tid] + s_redS[1][tid] + s_redS[2][tid] + s_redS[3][tid] + conf_b2[0])));
        out[row0 + tid] = sc[4] + sc[9] + gamma * sc[10];
    }
}

// ---------------------------------------------------------------------------
extern "C" void kernel_launch(void* const* d_in, const int* in_sizes, int n_in,
                              void* d_out, int out_size, void* d_ws, size_t ws_size,
                              hipStream_t stream)
{
    const float* x_num   = (const float*)d_in[0];
    const float* center  = (const float*)d_in[1];
    const float* scale   = (const float*)d_in[2];
    const float* qs      = (const float*)d_in[3];
    const float* stem_w1 = (const float*)d_in[4];
    const float* stem_b1 = (const float*)d_in[5];
    const float* stem_w2 = (const float*)d_in[6];
    const float* stem_b2 = (const float*)d_in[7];
    const float* stem_w3 = (const float*)d_in[8];
    const float* stem_b3 = (const float*)d_in[9];
    const float* gate_w1 = (const float*)d_in[10];
    const float* gate_b1 = (const float*)d_in[11];
    const float* gate_w2 = (const float*)d_in[12];
    const float* gate_b2 = (const float*)d_in[13];
    const float* bb_w    = (const float*)d_in[14];
    const float* bb_b    = (const float*)d_in[15];
    const float* base_w  = (const float*)d_in[16];
    const float* base_b  = (const float*)d_in[17];
    const float* safe_lg = (const float*)d_in[18];
    const float* safe_lb = (const float*)d_in[19];
    const float* safe_w1 = (const float*)d_in[20];
    const float* safe_b1 = (const float*)d_in[21];
    const float* safe_w2 = (const float*)d_in[22];
    const float* safe_b2 = (const float*)d_in[23];
    const float* top_w1  = (const float*)d_in[24];
    const float* top_b1  = (const float*)d_in[25];
    const float* top_w2  = (const float*)d_in[26];
    const float* top_b2  = (const float*)d_in[27];
    const float* spec_lg = (const float*)d_in[28];
    const float* spec_lb = (const float*)d_in[29];
    const float* spec_w1 = (const float*)d_in[30];
    const float* spec_b1 = (const float*)d_in[31];
    const float* spec_w2 = (const float*)d_in[32];
    const float* spec_b2 = (const float*)d_in[33];
    const float* conf_lg = (const float*)d_in[34];
    const float* conf_lb = (const float*)d_in[35];
    const float* conf_w1 = (const float*)d_in[36];
    const float* conf_b1 = (const float*)d_in[37];
    const float* conf_w2 = (const float*)d_in[38];
    const float* conf_b2 = (const float*)d_in[39];

    float* ws    = (float*)d_ws;
    float* x_cal = ws;                         // layout keeper
    float* g_h   = x_cal + (long)B * 256;      // -> x_bf
    float* g     = g_h   + (long)B * 128;      // unused
    float* h_b   = g     + (long)B * 256;      // -> qs_t
    float* z_top = h_b   + (long)B * 256;      // unused
    float* gstat = z_top + (long)B * 16;       // unused
    short* w1t   = (short*)(gstat + (long)B * 4);
    short* w2t   = w1t   + 128 * 256;
    short* bbt   = w2t   + 256 * 128;
    short* sw1t  = bbt   + 256 * 256;
    short* spw1t = sw1t  + 128 * 256;
    short* cfw1t = spw1t + 128 * 288;
    float* qs_t  = h_b;
    short* x_bf  = (short*)g_h;
    float* out   = (float*)d_out;

    k_prepall<<<2976, 256, 0, stream>>>(gate_w1, gate_w2, bb_w, safe_w1, spec_w1,
                                        conf_w1, qs,
                                        w1t, w2t, bbt, sw1t, spw1t, cfw1t, qs_t);
    k_calib9<<<dim3(512, 2), 256, 0, stream>>>(x_num, center, scale, qs, qs_t,
                                               stem_w1, stem_b1, stem_w2, stem_b2,
                                               stem_w3, stem_b3, x_bf);
    k_mega<<<B / MR, 256, 0, stream>>>(x_bf,
                                       w1t, gate_b1, w2t, gate_b2, bbt, bb_b,
                                       base_w, base_b,
                                       top_w1, top_b1, top_w2, top_b2,
                                       safe_lg, safe_lb, sw1t, safe_b1, safe_w2, safe_b2,
                                       spec_lg, spec_lb, spw1t, spec_b1, spec_w2, spec_b2,
                                       conf_lg, conf_lb, cfw1t, conf_b1, conf_w2, conf_b2,
                                       out);
}